// Round 12
// baseline (50.552 us; speedup 1.0000x reference)
//
#include <hip/hip_runtime.h>

#define TPB 512                        // 8 waves; each wave owns 32 rows (half-row lanes)
#define CHUNK_ROWS 256
#define ROW_F 25
#define CHUNK_F (CHUNK_ROWS * ROW_F)   // 6400 floats per array per chunk
#define CHUNK_F4 (CHUNK_F / 4)         // 1600 float4 per array per chunk

// Slim judge for ONE group: ranks of out == ranks of pre (softmax monotone);
// "within" in scaled form |3*e_i - t_i*S| <= 0.09*S (no divide in the chain).
__device__ __forceinline__ void judge_group(const float* __restrict__ p,
                                            const float* __restrict__ t,
                                            int& calc, int& acc) {
    const float GAPv = 0.03f;   // 3 * 0.01
    float p0 = p[0], p1 = p[1], p2 = p[2], p3 = p[3];
    float t0 = t[0], t1 = t[1], t2 = t[2], t3 = t[3];

    float m  = fmaxf(fmaxf(p0, p1), fmaxf(p2, p3));
    float e0 = __expf(p0 - m), e1 = __expf(p1 - m);
    float e2 = __expf(p2 - m), e3 = __expf(p3 - m);
    float S  = (e0 + e1) + (e2 + e3);
    float thr = 0.09f * S;
    float w0 = fmaf(3.0f, e0, -t0 * S);
    float w1 = fmaf(3.0f, e1, -t1 * S);
    float w2 = fmaf(3.0f, e2, -t2 * S);
    float w3 = fmaf(3.0f, e3, -t3 * S);
    bool within = fabsf(w0) <= thr && fabsf(w1) <= thr &&
                  fabsf(w2) <= thr && fabsf(w3) <= thr;

    // stable ranks of p (== ranks of out). g_ij = (p_j < p_i), i<j.
    int g01 = p1 < p0, g02 = p2 < p0, g03 = p3 < p0;
    int g12 = p2 < p1, g13 = p3 < p1, g23 = p3 < p2;
    int ro0 = g01 + g02 + g03;
    int ro1 = 1 - g01 + g12 + g13;
    int ro2 = 2 - g02 - g12 + g23;
    int ro3 = 3 - g03 - g13 - g23;

    int h01 = t1 < t0, h02 = t2 < t0, h03 = t3 < t0;
    int h12 = t2 < t1, h13 = t3 < t1, h23 = t3 < t2;
    int rt0 = h01 + h02 + h03;
    int rt1 = 1 - h01 + h12 + h13;
    int rt2 = 2 - h02 - h12 + h23;
    int rt3 = 3 - h03 - h13 - h23;

    // sorted target values (ascending): st0 <= st1 <= st2
    float l01 = fminf(t0, t1), x01 = fmaxf(t0, t1);
    float l23 = fminf(t2, t3), x23 = fmaxf(t2, t3);
    float st0 = fminf(l01, l23), mlo = fmaxf(l01, l23);
    float mhi = fminf(x01, x23);
    float st1 = fminf(mlo, mhi), st2 = fmaxf(mlo, mhi);
    float d1 = st1 - st0;
    float d2 = st2 - st1;

    bool jump = within && (
        ((d1 < GAPv) & (d2 < GAPv)) ||
        ((d1 < GAPv) & (ro2 == rt2)) ||
        ((d2 < GAPv) & (ro0 == rt0)));

    int nz = (t0 == 0.0f) + (t1 == 0.0f) + (t2 == 0.0f) + (t3 == 0.0f);
    bool match_all = (ro0 == rt0) & (ro1 == rt1) & (ro2 == rt2) & (ro3 == rt3);

    bool s2 = ((ro0 == 2) & (rt0 == 2)) | ((ro1 == 2) & (rt1 == 2)) |
              ((ro2 == 2) & (rt2 == 2)) | ((ro3 == 2) & (rt3 == 2));
    bool s3 = ((ro0 == 3) & (rt0 == 3)) | ((ro1 == 3) & (rt1 == 3)) |
              ((ro2 == 3) & (rt2 == 3)) | ((ro3 == 3) & (rt3 == 3));

    bool c_lt2 = !jump & (nz < 2);
    bool c_eq2 = !jump & (nz == 2) & s2 & s3;
    bool c_eq3 = !jump & (nz == 3) & (ro3 == 3);

    calc += (jump | c_lt2 | c_eq2 | c_eq3) ? 1 : 0;
    acc  += (jump | (c_lt2 & match_all) | c_eq2 | c_eq3) ? 1 : 0;
}

__global__ __launch_bounds__(TPB)
void recall_main_kernel(const float* __restrict__ pre,
                        const float* __restrict__ tar,
                        unsigned int* __restrict__ totC,     // ws + 0
                        unsigned int* __restrict__ totV,     // ws + 128
                        unsigned int* __restrict__ counter,  // ws + 256
                        float* __restrict__ out,
                        int B, int nchunks, int grid) {
    __shared__ __align__(16) float s_pre[CHUNK_F];
    __shared__ __align__(16) float s_tar[CHUNK_F];
    __shared__ int s_red[16];

    const int t = threadIdx.x;
    const int lane = t & 63;
    const int wid  = t >> 6;
    const int total4 = (B * ROW_F) >> 2;

    const float4* pre4 = (const float4*)pre;
    const float4* tar4 = (const float4*)tar;
    float4* sp4 = (float4*)s_pre;
    float4* st4 = (float4*)s_tar;

    // half-row mapping: lanes l and l+32 share row (wid*32 + (l&31));
    // lane half h judges groups [3h, 3h+3) = floats [12h, 12h+12)
    const int row_local = (wid << 5) | (lane & 31);
    const int half = lane >> 5;
    const int off  = 12 * half;

    // integer-exact accumulation: row contribution acc/calc == acc*(60/calc)/60
    int csum = 0, vsum = 0;

    for (int c = blockIdx.x; c < nchunks; c += grid) {
        __syncthreads();   // previous iteration's LDS reads done before overwrite

        const int base4 = c * CHUNK_F4;

        if (base4 + CHUNK_F4 <= total4) {
            // full chunk: guard-free coalesced staging (1600 f4 per array)
#pragma unroll
            for (int k = 0; k < 3; ++k) {
                int j = k * TPB + t;
                sp4[j] = pre4[base4 + j];
                st4[j] = tar4[base4 + j];
            }
            if (t < CHUNK_F4 - 3 * TPB) {          // remaining 64 f4
                int j = 3 * TPB + t;
                sp4[j] = pre4[base4 + j];
                st4[j] = tar4[base4 + j];
            }
        } else {
            // tail chunk: guarded (clamped rows are >= B, never used)
#pragma unroll
            for (int k = 0; k < 4; ++k) {
                int j = k * TPB + t;
                if (j < CHUNK_F4) {
                    int gi = base4 + j;
                    if (gi >= total4) gi = total4 - 1;
                    sp4[j] = pre4[gi];
                    st4[j] = tar4[gi];
                }
            }
        }
        __syncthreads();

        int row = c * CHUNK_ROWS + row_local;
        if (row < B) {
            const float* rp = &s_pre[row_local * ROW_F + off];
            const float* rt = &s_tar[row_local * ROW_F + off];
            int calc = 0, acc = 0;
            judge_group(rp,     rt,     calc, acc);
            judge_group(rp + 4, rt + 4, calc, acc);
            judge_group(rp + 8, rt + 8, calc, acc);
            // merge lane pair (l, l+32): one packed shuffle
            int pack  = (acc << 8) | calc;
            int other = __shfl_xor(pack, 32);
            calc += other & 0xff;
            acc  += other >> 8;
            if (half == 0 && calc > 0) {
                int inv = (calc == 1) ? 60 : (calc == 2) ? 30 : (calc == 3) ? 20
                        : (calc == 4) ? 15 : (calc == 5) ? 12 : 10;   // 60/calc exact
                csum += acc * inv;
                vsum += 1;
            }
        }
    }

    // deterministic block reduction (integers, 8 waves)
#pragma unroll
    for (int offr = 32; offr > 0; offr >>= 1) {
        csum += __shfl_down(csum, offr);
        vsum += __shfl_down(vsum, offr);
    }
    if (lane == 0) { s_red[wid] = csum; s_red[8 + wid] = vsum; }
    __syncthreads();

    if (t == 0) {
        int bc = 0, bv = 0;
#pragma unroll
        for (int i = 0; i < 8; ++i) { bc += s_red[i]; bv += s_red[8 + i]; }

        // device-scope atomic adds (order-independent integers -> deterministic)
        unsigned int o1 = atomicAdd(totC, (unsigned int)bc);
        unsigned int o2 = atomicAdd(totV, (unsigned int)bv);
        // force completion of the two adds (they have reached the coherent
        // point once their old values are back) before signaling the counter
        asm volatile("" :: "v"(o1), "v"(o2));
        asm volatile("s_waitcnt vmcnt(0)" ::: "memory");

        unsigned int done = atomicAdd(counter, 1u);
        if (done == (unsigned int)grid - 1u) {
            // unique last block: totals are final at the coherent point
            unsigned int fc = atomicAdd(totC, 0u);
            unsigned int fv = atomicAdd(totV, 0u);
            out[0] = (fv > 0u) ? (float)((double)fc / (60.0 * (double)fv)) : 0.0f;
        }
    }
}

extern "C" void kernel_launch(void* const* d_in, const int* in_sizes, int n_in,
                              void* d_out, int out_size, void* d_ws, size_t ws_size,
                              hipStream_t stream) {
    const float* pre = (const float*)d_in[0];
    const float* tar = (const float*)d_in[1];
    float* out = (float*)d_out;
    unsigned int* totC    = (unsigned int*)d_ws;                  // separate cache lines
    unsigned int* totV    = (unsigned int*)((char*)d_ws + 128);
    unsigned int* counter = (unsigned int*)((char*)d_ws + 256);

    int B = in_sizes[0] / ROW_F;
    int nchunks = (B + CHUNK_ROWS - 1) / CHUNK_ROWS;

    int grid = 1536;
    if (grid > nchunks) grid = nchunks;
    if (grid < 1) grid = 1;

    hipMemsetAsync(d_ws, 0, 384, stream);   // totC, totV, counter
    recall_main_kernel<<<grid, TPB, 0, stream>>>(pre, tar, totC, totV, counter,
                                                 out, B, nchunks, grid);
}

// Round 13
// 41.010 us; speedup vs baseline: 1.2327x; 1.2327x over previous
//
#include <hip/hip_runtime.h>

#define TPB 256                        // 4 waves; half-row lanes -> 128 rows/chunk
#define CHUNK_ROWS 128
#define ROW_F 25
#define CHUNK_FA (CHUNK_ROWS * ROW_F)  // 3200 floats per array per chunk
#define CHUNK_F4A (CHUNK_FA / 4)       // 800 float4 per array per chunk
#define REM (CHUNK_F4A - 3 * TPB)      // 32 leftover f4 per array (t < 32)

// Slim judge for ONE group: ranks of out == ranks of pre (softmax monotone);
// "within" in scaled form |3*e_i - t_i*S| <= 0.09*S (no divide in the chain).
__device__ __forceinline__ void judge_group(const float* __restrict__ p,
                                            const float* __restrict__ t,
                                            int& calc, int& acc) {
    const float GAPv = 0.03f;   // 3 * 0.01
    float p0 = p[0], p1 = p[1], p2 = p[2], p3 = p[3];
    float t0 = t[0], t1 = t[1], t2 = t[2], t3 = t[3];

    float m  = fmaxf(fmaxf(p0, p1), fmaxf(p2, p3));
    float e0 = __expf(p0 - m), e1 = __expf(p1 - m);
    float e2 = __expf(p2 - m), e3 = __expf(p3 - m);
    float S  = (e0 + e1) + (e2 + e3);
    float thr = 0.09f * S;
    float w0 = fmaf(3.0f, e0, -t0 * S);
    float w1 = fmaf(3.0f, e1, -t1 * S);
    float w2 = fmaf(3.0f, e2, -t2 * S);
    float w3 = fmaf(3.0f, e3, -t3 * S);
    bool within = fabsf(w0) <= thr && fabsf(w1) <= thr &&
                  fabsf(w2) <= thr && fabsf(w3) <= thr;

    // stable ranks of p (== ranks of out). g_ij = (p_j < p_i), i<j.
    int g01 = p1 < p0, g02 = p2 < p0, g03 = p3 < p0;
    int g12 = p2 < p1, g13 = p3 < p1, g23 = p3 < p2;
    int ro0 = g01 + g02 + g03;
    int ro1 = 1 - g01 + g12 + g13;
    int ro2 = 2 - g02 - g12 + g23;
    int ro3 = 3 - g03 - g13 - g23;

    int h01 = t1 < t0, h02 = t2 < t0, h03 = t3 < t0;
    int h12 = t2 < t1, h13 = t3 < t1, h23 = t3 < t2;
    int rt0 = h01 + h02 + h03;
    int rt1 = 1 - h01 + h12 + h13;
    int rt2 = 2 - h02 - h12 + h23;
    int rt3 = 3 - h03 - h13 - h23;

    // sorted target values (ascending): st0 <= st1 <= st2
    float l01 = fminf(t0, t1), x01 = fmaxf(t0, t1);
    float l23 = fminf(t2, t3), x23 = fmaxf(t2, t3);
    float st0 = fminf(l01, l23), mlo = fmaxf(l01, l23);
    float mhi = fminf(x01, x23);
    float st1 = fminf(mlo, mhi), st2 = fmaxf(mlo, mhi);
    float d1 = st1 - st0;
    float d2 = st2 - st1;

    bool jump = within && (
        ((d1 < GAPv) & (d2 < GAPv)) ||
        ((d1 < GAPv) & (ro2 == rt2)) ||
        ((d2 < GAPv) & (ro0 == rt0)));

    int nz = (t0 == 0.0f) + (t1 == 0.0f) + (t2 == 0.0f) + (t3 == 0.0f);
    bool match_all = (ro0 == rt0) & (ro1 == rt1) & (ro2 == rt2) & (ro3 == rt3);

    bool s2 = ((ro0 == 2) & (rt0 == 2)) | ((ro1 == 2) & (rt1 == 2)) |
              ((ro2 == 2) & (rt2 == 2)) | ((ro3 == 2) & (rt3 == 2));
    bool s3 = ((ro0 == 3) & (rt0 == 3)) | ((ro1 == 3) & (rt1 == 3)) |
              ((ro2 == 3) & (rt2 == 3)) | ((ro3 == 3) & (rt3 == 3));

    bool c_lt2 = !jump & (nz < 2);
    bool c_eq2 = !jump & (nz == 2) & s2 & s3;
    bool c_eq3 = !jump & (nz == 3) & (ro3 == 3);

    calc += (jump | c_lt2 | c_eq2 | c_eq3) ? 1 : 0;
    acc  += (jump | (c_lt2 & match_all) | c_eq2 | c_eq3) ? 1 : 0;
}

__global__ __launch_bounds__(TPB, 3)
void recall_main_kernel(const float* __restrict__ pre,
                        const float* __restrict__ tar,
                        float* __restrict__ partial,
                        int B, int nchunks, int grid) {
    // double buffer: each buf = pre [0,3200) || tar [3200,6400) -> 2 x 25.6 KB
    __shared__ __align__(16) float s_buf[2][2 * CHUNK_FA];
    __shared__ float s_red[8];

    const int t    = threadIdx.x;
    const int lane = t & 63;
    const int wid  = t >> 6;
    const int total4 = (B * ROW_F) >> 2;   // per-array float4 count

    const float4* pre4 = (const float4*)pre;
    const float4* tar4 = (const float4*)tar;

    // half-row mapping: lanes l and l+32 share row (wid*32 + (l&31));
    // half h judges groups [3h, 3h+3) = floats [12h, 12h+12)
    const int row_local = (wid << 5) | (lane & 31);
    const int half = lane >> 5;
    const int off  = 12 * half;

    float csum = 0.0f, vsum = 0.0f;

    // named staging registers (never arrays -> never scratch)
    float4 a0, a1, a2, a3, b0, b1, b2, b3;

    // ---- load chunk c's 25.6 KB into registers (issue only; no wait) ----
    auto load_chunk = [&](int c) {
        const int base4 = c * CHUNK_F4A;
        if (base4 + CHUNK_F4A <= total4) {
            a0 = pre4[base4 + t];
            a1 = pre4[base4 + TPB + t];
            a2 = pre4[base4 + 2 * TPB + t];
            b0 = tar4[base4 + t];
            b1 = tar4[base4 + TPB + t];
            b2 = tar4[base4 + 2 * TPB + t];
            if (t < REM) {
                a3 = pre4[base4 + 3 * TPB + t];
                b3 = tar4[base4 + 3 * TPB + t];
            }
        } else {
            int g0 = base4 + t,          g1 = base4 + TPB + t;
            int g2 = base4 + 2 * TPB + t, g3 = base4 + 3 * TPB + t;
            if (g0 >= total4) g0 = total4 - 1;
            if (g1 >= total4) g1 = total4 - 1;
            if (g2 >= total4) g2 = total4 - 1;
            if (g3 >= total4) g3 = total4 - 1;
            a0 = pre4[g0]; a1 = pre4[g1]; a2 = pre4[g2];
            b0 = tar4[g0]; b1 = tar4[g1]; b2 = tar4[g2];
            if (t < REM) { a3 = pre4[g3]; b3 = tar4[g3]; }
        }
    };
    // ---- write staged registers into LDS buffer ----
    auto write_chunk = [&](float* buf) {
        float4* sp = (float4*)buf;                 // pre half
        float4* st = (float4*)(buf + CHUNK_FA);    // tar half
        sp[t] = a0; sp[TPB + t] = a1; sp[2 * TPB + t] = a2;
        st[t] = b0; st[TPB + t] = b1; st[2 * TPB + t] = b2;
        if (t < REM) { sp[3 * TPB + t] = a3; st[3 * TPB + t] = b3; }
    };

    // prologue: stage first chunk
    int c = blockIdx.x;
    load_chunk(c);
    write_chunk(s_buf[0]);
    __syncthreads();

    int cur = 0;
    for (; c < nchunks; c += grid) {
        const int nc = c + grid;
        const bool has_next = nc < nchunks;

        if (has_next) load_chunk(nc);        // loads fly during compute below

        int row = c * CHUNK_ROWS + row_local;
        if (row < B) {
            const float* rp = &s_buf[cur][row_local * ROW_F + off];
            const float* rt = rp + CHUNK_FA;
            int calc = 0, acc = 0;
            judge_group(rp,     rt,     calc, acc);
            judge_group(rp + 4, rt + 4, calc, acc);
            judge_group(rp + 8, rt + 8, calc, acc);
            // merge lane pair (l, l+32): one packed shuffle
            int pack  = (acc << 8) | calc;
            int other = __shfl_xor(pack, 32);
            calc += other & 0xff;
            acc  += other >> 8;
            if (half == 0 && calc > 0) {
                csum += __fdividef((float)acc, (float)calc);
                vsum += 1.0f;
            }
        }

        if (has_next) write_chunk(s_buf[cur ^ 1]);  // vmcnt waits land here
        __syncthreads();                             // one barrier per iteration
        cur ^= 1;
    }

    // deterministic block reduction (4 waves)
#pragma unroll
    for (int offr = 32; offr > 0; offr >>= 1) {
        csum += __shfl_down(csum, offr);
        vsum += __shfl_down(vsum, offr);
    }
    if (lane == 0) { s_red[wid] = csum; s_red[4 + wid] = vsum; }
    __syncthreads();
    if (t == 0) {
        partial[2 * blockIdx.x]     = s_red[0] + s_red[1] + s_red[2] + s_red[3];
        partial[2 * blockIdx.x + 1] = s_red[4] + s_red[5] + s_red[6] + s_red[7];
    }
}

__global__ __launch_bounds__(256)
void recall_finalize_kernel(const float* __restrict__ partial, int n,
                            float* __restrict__ out) {
    __shared__ float s_red[8];
    float c = 0.0f, v = 0.0f;
    for (int i = threadIdx.x; i < n; i += 256) {
        c += partial[2 * i];
        v += partial[2 * i + 1];
    }
#pragma unroll
    for (int off = 32; off > 0; off >>= 1) {
        c += __shfl_down(c, off);
        v += __shfl_down(v, off);
    }
    int wave = threadIdx.x >> 6;
    if ((threadIdx.x & 63) == 0) { s_red[wave] = c; s_red[4 + wave] = v; }
    __syncthreads();
    if (threadIdx.x == 0) {
        float cs = s_red[0] + s_red[1] + s_red[2] + s_red[3];
        float vs = s_red[4] + s_red[5] + s_red[6] + s_red[7];
        out[0] = (vs > 0.0f) ? (cs / vs) : 0.0f;
    }
}

extern "C" void kernel_launch(void* const* d_in, const int* in_sizes, int n_in,
                              void* d_out, int out_size, void* d_ws, size_t ws_size,
                              hipStream_t stream) {
    const float* pre = (const float*)d_in[0];
    const float* tar = (const float*)d_in[1];
    float* out = (float*)d_out;
    float* partial = (float*)d_ws;                 // 768*2*4 = 6 KB

    int B = in_sizes[0] / ROW_F;
    int nchunks = (B + CHUNK_ROWS - 1) / CHUNK_ROWS;

    // 3 blocks/CU (51.2 KB LDS each) x 256 CU = 768 blocks
    int grid = 768;
    if (grid > nchunks) grid = nchunks;
    if (grid < 1) grid = 1;

    recall_main_kernel<<<grid, TPB, 0, stream>>>(pre, tar, partial, B, nchunks, grid);
    recall_finalize_kernel<<<1, 256, 0, stream>>>(partial, grid, out);
}